// Round 12
// baseline (285.410 us; speedup 1.0000x reference)
//
#include <hip/hip_runtime.h>
#include <stdint.h>

#define MDIM 4096
#define KDIM 4096
#define NDIM 11008
#define KP   (KDIM/8)    // 512 packed int32 per N-row

typedef float  f32x4   __attribute__((ext_vector_type(4)));
typedef __bf16 bf16x8  __attribute__((ext_vector_type(8)));
typedef unsigned short u16x8 __attribute__((ext_vector_type(8)));
typedef int    i32x4   __attribute__((ext_vector_type(4)));
typedef int    i32x16  __attribute__((ext_vector_type(16)));
typedef char   c8x8    __attribute__((ext_vector_type(8)));
typedef char   c8x16   __attribute__((ext_vector_type(16)));

// RNE f32 -> bf16 bits (matches jax astype(bf16) for non-NaN inputs)
__device__ __forceinline__ unsigned short f2bf(float f) {
  uint32_t u = __builtin_bit_cast(uint32_t, f);
  u += 0x7FFFu + ((u >> 16) & 1u);
  return (unsigned short)(u >> 16);
}
__device__ __forceinline__ float bf2f(unsigned short h) {
  return __builtin_bit_cast(float, (uint32_t)h << 16);
}
__device__ __forceinline__ float bf16r(float f) { return bf2f(f2bf(f)); }

// async global -> LDS, 16B per lane, wave-uniform LDS base + lane*16
__device__ __forceinline__ void lds16(const void* g, void* l) {
  __builtin_amdgcn_global_load_lds(
      (const __attribute__((address_space(1))) unsigned int*)g,
      (__attribute__((address_space(3))) unsigned int*)l, 16, 0, 0);
}

// ---------------- pre-pass 1: unpack int4 words -> int8 Q8[N][K] ------------
__global__ __launch_bounds__(256) void repack_q_kernel(
    const uint32_t* __restrict__ wq, c8x8* __restrict__ Q8) {
  int idx = blockIdx.x * 256 + threadIdx.x;   // [0, N*KP)
  uint32_t w = wq[idx];
  c8x8 v;
#pragma unroll
  for (int j = 0; j < 8; ++j) v[j] = (char)((w >> (4 * j)) & 0xF);
  Q8[idx] = v;
}

// ---------------- pre-pass 2: x f32 -> per-row int8 + delta + exact bf16 sum
__global__ __launch_bounds__(256) void quant_x_kernel(
    const float* __restrict__ x, c8x16* __restrict__ X8,
    float* __restrict__ delta, float* __restrict__ xsum) {
  __shared__ float red[256];
  const int row = blockIdx.x, t = threadIdx.x;
  const float4* xr = (const float4*)(x + (size_t)row * KDIM);
  float xb[16];
#pragma unroll
  for (int i = 0; i < 4; ++i) {
    float4 f = xr[t * 4 + i];
    xb[i * 4 + 0] = bf16r(f.x); xb[i * 4 + 1] = bf16r(f.y);
    xb[i * 4 + 2] = bf16r(f.z); xb[i * 4 + 3] = bf16r(f.w);
  }
  float mx = 0.f, sm = 0.f;
#pragma unroll
  for (int j = 0; j < 16; ++j) { mx = fmaxf(mx, fabsf(xb[j])); sm += xb[j]; }
  red[t] = mx; __syncthreads();
  for (int o = 128; o > 0; o >>= 1) {
    if (t < o) red[t] = fmaxf(red[t], red[t + o]);
    __syncthreads();
  }
  const float rmx = red[0];
  __syncthreads();
  red[t] = sm; __syncthreads();
  for (int o = 128; o > 0; o >>= 1) {
    if (t < o) red[t] += red[t + o];
    __syncthreads();
  }
  const float rsm = red[0];
  const float inv = (rmx > 0.f) ? 127.0f / rmx : 0.f;
  if (t == 0) {
    delta[row] = (rmx > 0.f) ? rmx / 127.0f : 0.f;
    xsum[row]  = rsm;
  }
  c8x16 q;
#pragma unroll
  for (int j = 0; j < 16; ++j) q[j] = (char)__float2int_rn(xb[j] * inv);
  X8[(size_t)row * 256 + t] = q;
}

// ---------------- main GEMM: 128x256, BK=128, 8 waves, i8 32x32x32 ----------
// r11 structure with the RACE FIXED: r11 placed the vmcnt waits at p0/p2 —
// AFTER the ds_reads of the freshly-staged slot in program order. s_waitcnt
// only blocks later issue; the already-issued ds_reads raced the
// global_load_lds DMA -> stale LDS (absmax 72). Invariant restored (as in
// r8/r10): the VMWAIT that retires a half executes one phase BEFORE that
// half's first ds_read, with a barrier in between. Waits now at p1/p3:
//   p1 VMWAIT(3) retires (T,h1)   (first read at p2)
//   p3 VMWAIT(3) retires (T+1,h0) (first read at next tile's p0)
// Trace: prologue 9 loads, VMWAIT(6) -> (0,h0) ready. Steady state enters
// each tile with 3 outstanding: p0 +1=4, p1 +2=6 -> VM(3) -> 3, p2 +1=4,
// p3 +2=6 -> VM(3) -> 3. TILE(0): STG01=0, waits (3,3). TILE(31): VM(0)/none.
// 3-slot ring (72KB LDS -> 2 blocks/CU, independent barrier domains fill
// each other's stalls — m114). Slot(tile,h) = (2*tile+h) % 3. A ring 3x8KB
// at 0; B ring 3x16KB at +24KB. Subtile swizzle verbatim r10 (0-conflict
// measured): chunk selector b3, odd-subtile ^1; read content check: position
// (2*(b3^ks)+(hk^sub)) holds chunk (2ks+hk) = the fragment's k-slice.
__global__ __launch_bounds__(512, 4) void gemm_i8_kernel(
    const char* __restrict__ A8, const char* __restrict__ Q8,
    const float* __restrict__ delta, const float* __restrict__ xsum,
    const float* __restrict__ scales, const float* __restrict__ zeros,
    const float* __restrict__ bias, float* __restrict__ out) {
  __shared__ __align__(16) char smem[73728];   // A 24KB | B 48KB

  const int tid  = threadIdx.x;
  const int lane = tid & 63;
  const int wave = tid >> 6;     // 0..7
  const int wm   = wave >> 2;    // 0..1 : M half (64 rows)
  const int wn   = wave & 3;     // 0..3 : N quarter (64 cols)

  // XCD-aware bijective swizzle: 1376 = 8 * 172 blocks; blocks on one XCD
  // share A panels (172 consecutive swz span ~4 m-tiles).
  const int b   = blockIdx.x;
  const int swz = (b & 7) * 172 + (b >> 3);
  const int mt  = swz / 43;
  const int nt  = swz - mt * 43;
  const int bm0 = mt * 128, bn0 = nt * 256;

  // staging geometry (r10 pattern): lane l writes subtile bytes [l*16,+16);
  // stored position schunk holds global chunk schunk ^ (b3(srow)<<1) ^ parity.
  const int srow   = lane >> 2;
  const int schunk = lane & 3;
  const int p0c    = schunk ^ (((srow >> 3) & 1) << 1);
  // A: wave stages subtile 'wave' (rows wave*16..+15), parity wave&1
  const char* aRw = A8 + (size_t)(bm0 + wave * 16 + srow) * KDIM
                       + (size_t)((p0c ^ (wave & 1)) * 16);
  // B: wave stages subtiles 2w (parity 0) and 2w+1 (parity 1)
  const char* bR  = Q8 + (size_t)(bn0 + wave * 32 + srow) * KDIM
                       + (size_t)(p0c * 16);
  const char* bR2 = Q8 + (size_t)(bn0 + wave * 32 + 16 + srow) * KDIM
                       + (size_t)((p0c ^ 1) * 16);

  // fragment read offsets (r10-proven zero-conflict pattern)
  const int r31 = lane & 31;
  const int sub = r31 >> 4;
  const int r15 = r31 & 15;
  const int hk  = lane >> 5;
  const int rd0 = sub * 1024 + r15 * 64 + ((hk ^ sub) << 4) + ((r15 & 8) << 2);
  const int rd1 = rd0 ^ 32;

  const int apair = (wm << 1);   // A subtile-pair base index (+mf)
  const int bpair = (wn << 1);   // B subtile-pair base index (+nf)

  i32x16 acc[2][2];
#pragma unroll
  for (int i = 0; i < 2; ++i)
#pragma unroll
    for (int j = 0; j < 2; ++j)
#pragma unroll
      for (int r = 0; r < 16; ++r) acc[i][j][r] = 0;

  i32x4 Af[2], Bf[2];

#define ABASE(S) ((S) * 8192)
#define BBASE(S) (24576 + (S) * 16384)

#define STAGE_A(tile, h, slot)                                              \
  lds16(aRw + (size_t)((tile) * 128 + (h) * 64),                            \
        smem + ABASE(slot) + wave * 1024)

#define STAGE_B(tile, h, slot)                                              \
  do {                                                                      \
    const size_t ko_ = (size_t)((tile) * 128 + (h) * 64);                   \
    char* d_ = smem + BBASE(slot) + wave * 2048;                            \
    lds16(bR + ko_, d_);                                                    \
    lds16(bR2 + ko_, d_ + 1024);                                            \
  } while (0)

#define READ4(S, KS)                                                        \
  do {                                                                      \
    const int ro_ = (KS) ? rd1 : rd0;                                       \
    _Pragma("unroll") for (int mf = 0; mf < 2; ++mf)                        \
        Af[mf] = *(const i32x4*)(smem + ABASE(S) +                          \
                                 (apair + mf) * 2048 + ro_);                \
    _Pragma("unroll") for (int nf = 0; nf < 2; ++nf)                        \
        Bf[nf] = *(const i32x4*)(smem + BBASE(S) +                          \
                                 (bpair + nf) * 2048 + ro_);                \
  } while (0)

#define MFMA4()                                                             \
  __builtin_amdgcn_s_setprio(1);                                            \
  _Pragma("unroll") for (int mf = 0; mf < 2; ++mf)                          \
      _Pragma("unroll") for (int nf = 0; nf < 2; ++nf)                      \
          acc[mf][nf] = __builtin_amdgcn_mfma_i32_32x32x32_i8(              \
              Af[mf], Bf[nf], acc[mf][nf], 0, 0, 0);                        \
  __builtin_amdgcn_s_setprio(0);

#define BAR                                                                 \
  __builtin_amdgcn_s_barrier();                                             \
  __builtin_amdgcn_sched_barrier(0);

#define VMWAIT(N) asm volatile("s_waitcnt vmcnt(" #N ")" ::: "memory")

  // TILE: S0/S1 = slots of (T,h0)/(T,h1); SA = third slot for (T+1,h0);
  // (T+1,h1) recycles into S0 (one-barrier WAR separation after p1's MFMA).
  // VM1 (p1) retires (T,h1) BEFORE p2 reads it; VM3 (p3) retires (T+1,h0)
  // BEFORE next tile's p0 reads it. Waits always precede the dependent read
  // by one phase + barrier (the r8/r10 invariant).
#define TILE(T, S0, S1, SA, STG01, STG23, VM1STMT, VM3STMT)                 \
  do {                                                                      \
    READ4(S0, 0);                                                           \
    if (STG01) STAGE_A((T) + 1, 0, SA);                                     \
    BAR; MFMA4(); BAR;                                                      \
    READ4(S0, 1);                                                           \
    if (STG01) STAGE_B((T) + 1, 0, SA);                                     \
    VM1STMT;                                                                \
    BAR; MFMA4(); BAR;                                                      \
    READ4(S1, 0);                                                           \
    if (STG23) STAGE_A((T) + 1, 1, S0);                                     \
    BAR; MFMA4(); BAR;                                                      \
    READ4(S1, 1);                                                           \
    if (STG23) STAGE_B((T) + 1, 1, S0);                                     \
    VM3STMT;                                                                \
    BAR; MFMA4(); BAR;                                                      \
  } while (0)

  // prologue: (0,h0)->slot0, (0,h1)->slot1, (1,h0)->slot2 = 9 loads;
  // retire the first 3 ((0,h0) ready).
  STAGE_A(0, 0, 0); STAGE_B(0, 0, 0);
  STAGE_A(0, 1, 1); STAGE_B(0, 1, 1);
  STAGE_A(1, 0, 2); STAGE_B(1, 0, 2);
  VMWAIT(6);
  BAR;

  // T=0: (1,h0) already staged -> STG01=0; stage only (1,h1)->slot0.
  // VM1=VMWAIT(3) retires (0,h1) before p2; VM3=VMWAIT(3) retires (1,h0).
  TILE(0, 0, 1, 2, 0, 1, VMWAIT(3), VMWAIT(3));
  // T = 1..30, slot pattern period 3: T%3==1:(2,0,1); ==2:(1,2,0); ==0:(0,1,2)
  for (int tt = 1; tt < 28; tt += 3) {
    TILE(tt,     2, 0, 1, 1, 1, VMWAIT(3), VMWAIT(3));
    TILE(tt + 1, 1, 2, 0, 1, 1, VMWAIT(3), VMWAIT(3));
    TILE(tt + 2, 0, 1, 2, 1, 1, VMWAIT(3), VMWAIT(3));
  }
  TILE(28, 2, 0, 1, 1, 1, VMWAIT(3), VMWAIT(3));
  TILE(29, 1, 2, 0, 1, 1, VMWAIT(3), VMWAIT(3));
  TILE(30, 0, 1, 2, 1, 1, VMWAIT(3), VMWAIT(3));  // stages (31,h0)->2,(31,h1)->0
  TILE(31, 2, 0, 1, 0, 0, VMWAIT(0), (void)0);    // drain (31,h1) before p2

#undef TILE
#undef VMWAIT
#undef BAR
#undef MFMA4
#undef READ4
#undef STAGE_B
#undef STAGE_A
#undef BBASE
#undef ABASE

  // epilogue: C/D 32x32 layout col=lane&31, row=(reg&3)+8*(reg>>2)+4*(lane>>5)
  // out = acc * (Delta_m * bf16(s_n)) + bf16(z_n) * xsum_m + bias_n
  const int colv = bn0 + wn * 64 + (lane & 31);
  const int rowb = bm0 + wm * 64 + ((lane >> 5) << 2);
  float sb[2], zb[2], bv[2];
#pragma unroll
  for (int nf = 0; nf < 2; ++nf) {
    sb[nf] = bf16r(scales[colv + nf * 32]);
    zb[nf] = bf16r(zeros[colv + nf * 32]);
    bv[nf] = bias[colv + nf * 32];
  }
#pragma unroll
  for (int mf = 0; mf < 2; ++mf)
#pragma unroll
    for (int reg = 0; reg < 16; ++reg) {
      const int row = rowb + mf * 32 + (reg & 3) + ((reg >> 2) << 3);
      const float dm = delta[row];
      const float xm = xsum[row];
#pragma unroll
      for (int nf = 0; nf < 2; ++nf)
        out[(size_t)row * NDIM + colv + nf * 32] =
            (float)acc[mf][nf][reg] * (dm * sb[nf]) + (zb[nf] * xm + bv[nf]);
    }
}

// ---------------- fallback fused 128x128 bf16 kernel (ws too small) ---------
__global__ __launch_bounds__(256, 3) void gemm_fused_kernel(
    const float* __restrict__ x, const uint32_t* __restrict__ wq,
    const float* __restrict__ scales, const float* __restrict__ zeros,
    const float* __restrict__ bias, float* __restrict__ out) {
  __shared__ __align__(16) char smem[2 * 128 * 64 * 2];
  char* As = smem;
  char* Bs = smem + 16384;

  const int tid  = threadIdx.x;
  const int lane = tid & 63;
  const int wave = tid >> 6;
  const int wm = wave >> 1, wn = wave & 1;

  const int b   = blockIdx.x;
  const int swz = (b & 7) * 344 + (b >> 3);
  const int mt  = swz / 86;
  const int nt  = swz - mt * 86;
  const int bm0 = mt * 128, bn0 = nt * 128;

  f32x4 acc[4][4];
#pragma unroll
  for (int i = 0; i < 4; ++i)
#pragma unroll
    for (int j = 0; j < 4; ++j) acc[i][j] = (f32x4){0.f, 0.f, 0.f, 0.f};

  const int base_a = ((wm * 64 + (lane & 15)) << 7) + ((lane >> 4) << 4);
  const int base_b = ((wn * 64 + (lane & 15)) << 7) + ((lane >> 4) << 4);

  float sv[4], zv[4];
#pragma unroll
  for (int it = 0; it < 4; ++it) {
    int r = bn0 + it * 32 + (tid >> 3);
    sv[it] = bf16r(scales[r]);
    zv[it] = bf16r(zeros[r]);
  }

  for (int kt = 0; kt < KDIM / 64; ++kt) {
    const int k0 = kt * 64;
    __syncthreads();
#pragma unroll
    for (int it = 0; it < 4; ++it) {
      int ch = it * 256 + tid;
      int row = ch >> 3, c8 = ch & 7;
      const float* src = x + (size_t)(bm0 + row) * KDIM + k0 + c8 * 8;
      float4 f0 = *(const float4*)src;
      float4 f1 = *(const float4*)(src + 4);
      u16x8 v;
      v[0] = f2bf(f0.x); v[1] = f2bf(f0.y); v[2] = f2bf(f0.z); v[3] = f2bf(f0.w);
      v[4] = f2bf(f1.x); v[5] = f2bf(f1.y); v[6] = f2bf(f1.z); v[7] = f2bf(f1.w);
      *(u16x8*)(As + row * 128 + c8 * 16) = v;
    }
#pragma unroll
    for (int it = 0; it < 4; ++it) {
      int ch = it * 256 + tid;
      int row = ch >> 3, kp = ch & 7;
      uint32_t w = wq[(size_t)(bn0 + row) * KP + kt * 8 + kp];
      float s = sv[it], z = zv[it];
      u16x8 v;
#pragma unroll
      for (int j = 0; j < 8; ++j) {
        float qf = (float)((w >> (4 * j)) & 0xF);
        float t  = bf16r(qf * s);
        v[j] = f2bf(t + z);
      }
      *(u16x8*)(Bs + row * 128 + kp * 16) = v;
    }
    __syncthreads();
#pragma unroll
    for (int ks = 0; ks < 2; ++ks) {
      bf16x8 af[4], bf[4];
#pragma unroll
      for (int i = 0; i < 4; ++i)
        af[i] = *(const bf16x8*)(As + base_a + i * 2048 + ks * 64);
#pragma unroll
      for (int j = 0; j < 4; ++j)
        bf[j] = *(const bf16x8*)(Bs + base_b + j * 2048 + ks * 64);
#pragma unroll
      for (int i = 0; i < 4; ++i)
#pragma unroll
        for (int j = 0; j < 4; ++j)
          acc[i][j] = __builtin_amdgcn_mfma_f32_16x16x32_bf16(af[i], bf[j],
                                                              acc[i][j], 0, 0, 0);
    }
  }

  const int colbase = bn0 + wn * 64 + (lane & 15);
  const int rowbase = bm0 + wm * 64 + ((lane >> 4) << 2);
  float bv[4];
#pragma unroll
  for (int j = 0; j < 4; ++j) bv[j] = bias[colbase + j * 16];
#pragma unroll
  for (int i = 0; i < 4; ++i) {
#pragma unroll
    for (int j = 0; j < 4; ++j) {
      size_t base = (size_t)(rowbase + i * 16) * NDIM + colbase + j * 16;
#pragma unroll
      for (int r = 0; r < 4; ++r)
        out[base + (size_t)r * NDIM] = acc[i][j][r] + bv[j];
    }
  }
}

extern "C" void kernel_launch(void* const* d_in, const int* in_sizes, int n_in,
                              void* d_out, int out_size, void* d_ws, size_t ws_size,
                              hipStream_t stream) {
  const float*    x      = (const float*)d_in[0];
  const uint32_t* wq     = (const uint32_t*)d_in[1];
  const float*    scales = (const float*)d_in[2];
  const float*    zeros  = (const float*)d_in[3];
  const float*    bias   = (const float*)d_in[4];
  float*          out    = (float*)d_out;

  const size_t offQ = 0;
  const size_t szQ  = (size_t)NDIM * KDIM;           // 45,088,768
  const size_t offX = szQ;
  const size_t szX  = (size_t)MDIM * KDIM;           // 16,777,216
  const size_t offD = offX + szX;                    // 61,865,984
  const size_t offS = offD + MDIM * sizeof(float);
  const size_t need = offS + MDIM * sizeof(float);   // ~61.9 MB

  if (ws_size >= need) {
    char*  Q8    = (char*)d_ws + offQ;
    char*  X8    = (char*)d_ws + offX;
    float* dlt   = (float*)((char*)d_ws + offD);
    float* xsm   = (float*)((char*)d_ws + offS);
    repack_q_kernel<<<(NDIM * KP) / 256, 256, 0, stream>>>(wq, (c8x8*)Q8);
    quant_x_kernel<<<MDIM, 256, 0, stream>>>(x, (c8x16*)X8, dlt, xsm);
    gemm_i8_kernel<<<1376, 512, 0, stream>>>(X8, Q8, dlt, xsm, scales, zeros,
                                             bias, out);
  } else {
    gemm_fused_kernel<<<2752, 256, 0, stream>>>(x, wq, scales, zeros, bias, out);
  }
}

// Round 13
// 234.210 us; speedup vs baseline: 1.2186x; 1.2186x over previous
//
#include <hip/hip_runtime.h>
#include <stdint.h>

#define MDIM 4096
#define KDIM 4096
#define NDIM 11008
#define KP   (KDIM/8)    // 512 packed int32 per N-row

typedef float  f32x4   __attribute__((ext_vector_type(4)));
typedef __bf16 bf16x8  __attribute__((ext_vector_type(8)));
typedef unsigned short u16x8 __attribute__((ext_vector_type(8)));
typedef int    i32x4   __attribute__((ext_vector_type(4)));
typedef int    i32x16  __attribute__((ext_vector_type(16)));
typedef char   c8x8    __attribute__((ext_vector_type(8)));
typedef char   c8x16   __attribute__((ext_vector_type(16)));

// RNE f32 -> bf16 bits (matches jax astype(bf16) for non-NaN inputs)
__device__ __forceinline__ unsigned short f2bf(float f) {
  uint32_t u = __builtin_bit_cast(uint32_t, f);
  u += 0x7FFFu + ((u >> 16) & 1u);
  return (unsigned short)(u >> 16);
}
__device__ __forceinline__ float bf2f(unsigned short h) {
  return __builtin_bit_cast(float, (uint32_t)h << 16);
}
__device__ __forceinline__ float bf16r(float f) { return bf2f(f2bf(f)); }

// async global -> LDS, 16B per lane, wave-uniform LDS base + lane*16
__device__ __forceinline__ void lds16(const void* g, void* l) {
  __builtin_amdgcn_global_load_lds(
      (const __attribute__((address_space(1))) unsigned int*)g,
      (__attribute__((address_space(3))) unsigned int*)l, 16, 0, 0);
}

// ---------------- pre-pass 1: unpack int4 words -> int8 Q8[N][K] ------------
__global__ __launch_bounds__(256) void repack_q_kernel(
    const uint32_t* __restrict__ wq, c8x8* __restrict__ Q8) {
  int idx = blockIdx.x * 256 + threadIdx.x;   // [0, N*KP)
  uint32_t w = wq[idx];
  c8x8 v;
#pragma unroll
  for (int j = 0; j < 8; ++j) v[j] = (char)((w >> (4 * j)) & 0xF);
  Q8[idx] = v;
}

// ---------------- pre-pass 2: x f32 -> per-row int8 + delta + exact bf16 sum
__global__ __launch_bounds__(256) void quant_x_kernel(
    const float* __restrict__ x, c8x16* __restrict__ X8,
    float* __restrict__ delta, float* __restrict__ xsum) {
  __shared__ float red[256];
  const int row = blockIdx.x, t = threadIdx.x;
  const float4* xr = (const float4*)(x + (size_t)row * KDIM);
  float xb[16];
#pragma unroll
  for (int i = 0; i < 4; ++i) {
    float4 f = xr[t * 4 + i];
    xb[i * 4 + 0] = bf16r(f.x); xb[i * 4 + 1] = bf16r(f.y);
    xb[i * 4 + 2] = bf16r(f.z); xb[i * 4 + 3] = bf16r(f.w);
  }
  float mx = 0.f, sm = 0.f;
#pragma unroll
  for (int j = 0; j < 16; ++j) { mx = fmaxf(mx, fabsf(xb[j])); sm += xb[j]; }
  red[t] = mx; __syncthreads();
  for (int o = 128; o > 0; o >>= 1) {
    if (t < o) red[t] = fmaxf(red[t], red[t + o]);
    __syncthreads();
  }
  const float rmx = red[0];
  __syncthreads();
  red[t] = sm; __syncthreads();
  for (int o = 128; o > 0; o >>= 1) {
    if (t < o) red[t] += red[t + o];
    __syncthreads();
  }
  const float rsm = red[0];
  const float inv = (rmx > 0.f) ? 127.0f / rmx : 0.f;
  if (t == 0) {
    delta[row] = (rmx > 0.f) ? rmx / 127.0f : 0.f;
    xsum[row]  = rsm;
  }
  c8x16 q;
#pragma unroll
  for (int j = 0; j < 16; ++j) q[j] = (char)__float2int_rn(xb[j] * inv);
  X8[(size_t)row * 256 + t] = q;
}

// ---------------- main GEMM: 256x256, BK=128, 4 waves, i8 32x32x32 ----------
// r10 frame (4-slot ring, proven swizzle + slot/vmcnt schedule) with FOUR
// waves of 128x128 output each (2x2 wave grid, acc 4x4 x i32x16). Rationale
// from r10/r12 counters: per-CU LDS read volume = waves*(Wm+Wn)*BK; r10/r12
// both had Wm+Wn=192 (reads/MFMA 0.75-1.0) and the wall ~= MFMA + LDS
// serialized (r12: 89% LDS-pipe bound). 4 waves at 128x128 gives reads/MFMA
// = 0.5: per CU-tile LDS 1536 cyc < MFMA 2330 cyc -> MFMA-bound, with the
// wave's next-phase ds_reads overlapping its own MFMA tail (single-wave ILP).
// vmcnt schedule = r10's scaled x2 (stage group = 8 loads: A4+B4):
// prologue 24 loads VMWAIT(16); steady VMWAIT(16)@p1 retires (T,h1),
// VMWAIT(16)@p3 retires (T+1,h0); tail T30 (16)/(8), T31 (0)/none.
// Swizzle verbatim r10 (0-conflict measured): subtile 16r x 64B, chunk
// selector b3, odd-subtile ^1; per-wave read address set identical to r10.
__global__ __launch_bounds__(256, 1) void gemm_i8_kernel(
    const char* __restrict__ A8, const char* __restrict__ Q8,
    const float* __restrict__ delta, const float* __restrict__ xsum,
    const float* __restrict__ scales, const float* __restrict__ zeros,
    const float* __restrict__ bias, float* __restrict__ out) {
  __shared__ __align__(16) char smem[131072];  // A ring 4x16KB | B ring +64KB

  const int tid  = threadIdx.x;
  const int lane = tid & 63;
  const int wave = tid >> 6;     // 0..3
  const int wm   = wave >> 1;    // 0..1 : M half (128 rows)
  const int wn   = wave & 1;     // 0..1 : N half (128 cols)

  // XCD-aware bijective swizzle: 688 = 8 * 86 blocks (r10 verbatim).
  const int b   = blockIdx.x;
  const int swz = (b & 7) * 86 + (b >> 3);
  const int mt  = swz / 43;
  const int nt  = swz - mt * 43;
  const int bm0 = mt * 256, bn0 = nt * 256;

  // staging: lane l writes subtile bytes [l*16,+16); stored position schunk
  // holds global chunk schunk ^ (b3(srow)<<1) ^ parity(subtile).
  // Wave stages subtiles 4*wave + j (j=0..3), parity = j&1.
  const int srow   = lane >> 2;
  const int schunk = lane & 3;
  const int p0c    = schunk ^ (((srow >> 3) & 1) << 1);
  const char* aRe = A8 + (size_t)(bm0 + wave * 64 + srow) * KDIM + (size_t)(p0c * 16);
  const char* aRo = A8 + (size_t)(bm0 + wave * 64 + srow) * KDIM + (size_t)((p0c ^ 1) * 16);
  const char* bRe = Q8 + (size_t)(bn0 + wave * 64 + srow) * KDIM + (size_t)(p0c * 16);
  const char* bRo = Q8 + (size_t)(bn0 + wave * 64 + srow) * KDIM + (size_t)((p0c ^ 1) * 16);

  // fragment read offsets (r10-proven zero-conflict pattern)
  const int r31 = lane & 31;
  const int sub = r31 >> 4;
  const int r15 = r31 & 15;
  const int hk  = lane >> 5;
  const int rd0 = sub * 1024 + r15 * 64 + ((hk ^ sub) << 4) + ((r15 & 8) << 2);
  const int rd1 = rd0 ^ 32;

  const int aoffc = wm * 8192;          // wm*4 subtile-pairs (128 rows)
  const int boffc = 65536 + wn * 8192;  // B ring + wn*4 pairs (128 cols)

  i32x16 acc[4][4];
#pragma unroll
  for (int i = 0; i < 4; ++i)
#pragma unroll
    for (int j = 0; j < 4; ++j)
#pragma unroll
      for (int r = 0; r < 16; ++r) acc[i][j][r] = 0;

  i32x4 Af[4], Bf[4];

#define ABASE(S) ((S) << 14)
#define BBASE(S) (65536 + ((S) << 14))

#define STAGE_A(tile, h, slot)                                              \
  do {                                                                      \
    const size_t ko_ = (size_t)((tile) * 128 + (h) * 64);                   \
    char* d_ = smem + ABASE(slot) + wave * 4096;                            \
    lds16(aRe + ko_,                        d_);                            \
    lds16(aRo + (size_t)16 * KDIM + ko_,    d_ + 1024);                     \
    lds16(aRe + (size_t)32 * KDIM + ko_,    d_ + 2048);                     \
    lds16(aRo + (size_t)48 * KDIM + ko_,    d_ + 3072);                     \
  } while (0)

#define STAGE_B(tile, h, slot)                                              \
  do {                                                                      \
    const size_t ko_ = (size_t)((tile) * 128 + (h) * 64);                   \
    char* d_ = smem + BBASE(slot) + wave * 4096;                            \
    lds16(bRe + ko_,                        d_);                            \
    lds16(bRo + (size_t)16 * KDIM + ko_,    d_ + 1024);                     \
    lds16(bRe + (size_t)32 * KDIM + ko_,    d_ + 2048);                     \
    lds16(bRo + (size_t)48 * KDIM + ko_,    d_ + 3072);                     \
  } while (0)

#define READ8(S, KS)                                                        \
  do {                                                                      \
    const int ro_ = (KS) ? rd1 : rd0;                                       \
    _Pragma("unroll") for (int mf = 0; mf < 4; ++mf)                        \
        Af[mf] = *(const i32x4*)(smem + aoffc + ABASE(S) +                  \
                                 mf * 2048 + ro_);                          \
    _Pragma("unroll") for (int nf = 0; nf < 4; ++nf)                        \
        Bf[nf] = *(const i32x4*)(smem + boffc + ((S) << 14) +               \
                                 nf * 2048 + ro_);                          \
  } while (0)

#define MFMA16()                                                            \
  __builtin_amdgcn_s_setprio(1);                                            \
  _Pragma("unroll") for (int mf = 0; mf < 4; ++mf)                          \
      _Pragma("unroll") for (int nf = 0; nf < 4; ++nf)                      \
          acc[mf][nf] = __builtin_amdgcn_mfma_i32_32x32x32_i8(              \
              Af[mf], Bf[nf], acc[mf][nf], 0, 0, 0);                        \
  __builtin_amdgcn_s_setprio(0);

#define BAR                                                                 \
  __builtin_amdgcn_s_barrier();                                             \
  __builtin_amdgcn_sched_barrier(0);

#define VMWAIT(N) asm volatile("s_waitcnt vmcnt(" #N ")" ::: "memory")

  // TILE = r10's slot schedule: S0s/S1s = slots of (T,h0)/(T,h1); stage
  // (T+1,h1)->SN1s at p0/p1, (T+2,h0)->S0s at p2/p3 (one-barrier WAR sep).
  // Waits one phase before the dependent read (r8/r10 invariant).
#define TILE(T, S0s, S1s, SN1s, NSTG, VM1STMT, VM3STMT)                     \
  do {                                                                      \
    READ8(S0s, 0);                                                          \
    if ((NSTG) >= 1) STAGE_A((T) + 1, 1, SN1s);                             \
    BAR; MFMA16(); BAR;                                                     \
    READ8(S0s, 1);                                                          \
    if ((NSTG) >= 2) STAGE_B((T) + 1, 1, SN1s);                             \
    VM1STMT;                                                                \
    BAR; MFMA16(); BAR;                                                     \
    READ8(S1s, 0);                                                          \
    if ((NSTG) >= 3) STAGE_A((T) + 2, 0, S0s);                              \
    BAR; MFMA16(); BAR;                                                     \
    READ8(S1s, 1);                                                          \
    if ((NSTG) >= 4) STAGE_B((T) + 2, 0, S0s);                              \
    VM3STMT;                                                                \
    BAR; MFMA16(); BAR;                                                     \
  } while (0)

  // prologue: (0,h0)->s0, (0,h1)->s1, (1,h0)->s2 = 24 loads; retire first 8.
  STAGE_A(0, 0, 0); STAGE_B(0, 0, 0);
  STAGE_A(0, 1, 1); STAGE_B(0, 1, 1);
  STAGE_A(1, 0, 2); STAGE_B(1, 0, 2);
  VMWAIT(16);
  BAR;

  for (int tt = 0; tt < 30; tt += 2) {
    TILE(tt,     0, 1, 3, 4, VMWAIT(16), VMWAIT(16));
    TILE(tt + 1, 2, 3, 1, 4, VMWAIT(16), VMWAIT(16));
  }
  // T=30: stage only (31,h1); T=31: no staging, drain
  TILE(30, 0, 1, 3, 2, VMWAIT(16), VMWAIT(8));
  TILE(31, 2, 3, 1, 0, VMWAIT(0), (void)0);

#undef TILE
#undef VMWAIT
#undef BAR
#undef MFMA16
#undef READ8
#undef STAGE_B
#undef STAGE_A
#undef BBASE
#undef ABASE

  // epilogue: C/D 32x32 layout col=lane&31, row=(reg&3)+8*(reg>>2)+4*(lane>>5)
  // out = acc * (Delta_m * bf16(s_n)) + bf16(z_n) * xsum_m + bias_n
  const int colv = bn0 + wn * 128 + (lane & 31);
  const int rowb = bm0 + wm * 128 + ((lane >> 5) << 2);
  float sb[4], zb[4], bv[4];
#pragma unroll
  for (int nf = 0; nf < 4; ++nf) {
    sb[nf] = bf16r(scales[colv + nf * 32]);
    zb[nf] = bf16r(zeros[colv + nf * 32]);
    bv[nf] = bias[colv + nf * 32];
  }
#pragma unroll
  for (int mf = 0; mf < 4; ++mf)
#pragma unroll
    for (int reg = 0; reg < 16; ++reg) {
      const int row = rowb + mf * 32 + (reg & 3) + ((reg >> 2) << 3);
      const float dm = delta[row];
      const float xm = xsum[row];
#pragma unroll
      for (int nf = 0; nf < 4; ++nf)
        out[(size_t)row * NDIM + colv + nf * 32] =
            (float)acc[mf][nf][reg] * (dm * sb[nf]) + (zb[nf] * xm + bv[nf]);
    }
}

// ---------------- fallback fused 128x128 bf16 kernel (ws too small) ---------
__global__ __launch_bounds__(256, 3) void gemm_fused_kernel(
    const float* __restrict__ x, const uint32_t* __restrict__ wq,
    const float* __restrict__ scales, const float* __restrict__ zeros,
    const float* __restrict__ bias, float* __restrict__ out) {
  __shared__ __align__(16) char smem[2 * 128 * 64 * 2];
  char* As = smem;
  char* Bs = smem + 16384;

  const int tid  = threadIdx.x;
  const int lane = tid & 63;
  const int wave = tid >> 6;
  const int wm = wave >> 1, wn = wave & 1;

  const int b   = blockIdx.x;
  const int swz = (b & 7) * 344 + (b >> 3);
  const int mt  = swz / 86;
  const int nt  = swz - mt * 86;
  const int bm0 = mt * 128, bn0 = nt * 128;

  f32x4 acc[4][4];
#pragma unroll
  for (int i = 0; i < 4; ++i)
#pragma unroll
    for (int j = 0; j < 4; ++j) acc[i][j] = (f32x4){0.f, 0.f, 0.f, 0.f};

  const int base_a = ((wm * 64 + (lane & 15)) << 7) + ((lane >> 4) << 4);
  const int base_b = ((wn * 64 + (lane & 15)) << 7) + ((lane >> 4) << 4);

  float sv[4], zv[4];
#pragma unroll
  for (int it = 0; it < 4; ++it) {
    int r = bn0 + it * 32 + (tid >> 3);
    sv[it] = bf16r(scales[r]);
    zv[it] = bf16r(zeros[r]);
  }

  for (int kt = 0; kt < KDIM / 64; ++kt) {
    const int k0 = kt * 64;
    __syncthreads();
#pragma unroll
    for (int it = 0; it < 4; ++it) {
      int ch = it * 256 + tid;
      int row = ch >> 3, c8 = ch & 7;
      const float* src = x + (size_t)(bm0 + row) * KDIM + k0 + c8 * 8;
      float4 f0 = *(const float4*)src;
      float4 f1 = *(const float4*)(src + 4);
      u16x8 v;
      v[0] = f2bf(f0.x); v[1] = f2bf(f0.y); v[2] = f2bf(f0.z); v[3] = f2bf(f0.w);
      v[4] = f2bf(f1.x); v[5] = f2bf(f1.y); v[6] = f2bf(f1.z); v[7] = f2bf(f1.w);
      *(u16x8*)(As + row * 128 + c8 * 16) = v;
    }
#pragma unroll
    for (int it = 0; it < 4; ++it) {
      int ch = it * 256 + tid;
      int row = ch >> 3, kp = ch & 7;
      uint32_t w = wq[(size_t)(bn0 + row) * KP + kt * 8 + kp];
      float s = sv[it], z = zv[it];
      u16x8 v;
#pragma unroll
      for (int j = 0; j < 8; ++j) {
        float qf = (float)((w >> (4 * j)) & 0xF);
        float t  = bf16r(qf * s);
        v[j] = f2bf(t + z);
      }
      *(u16x8*)(Bs + row * 128 + kp * 16) = v;
    }
    __syncthreads();
#pragma unroll
    for (int ks = 0; ks < 2; ++ks) {
      bf16x8 af[4], bf[4];
#pragma unroll
      for (int i = 0; i < 4; ++i)
        af[i] = *(const bf16x8*)(As + base_a + i * 2048 + ks * 64);
#pragma unroll
      for (int j = 0; j < 4; ++j)
        bf[j] = *(const bf16x8*)(Bs + base_b + j * 2048 + ks * 64);
#pragma unroll
      for (int i = 0; i < 4; ++i)
#pragma unroll
        for (int j = 0; j < 4; ++j)
          acc[i][j] = __builtin_amdgcn_mfma_f32_16x16x32_bf16(af[i], bf[j],
                                                              acc[i][j], 0, 0, 0);
    }
  }

  const int colbase = bn0 + wn * 64 + (lane & 15);
  const int rowbase = bm0 + wm * 64 + ((lane >> 4) << 2);
  float bv[4];
#pragma unroll
  for (int j = 0; j < 4; ++j) bv[j] = bias[colbase + j * 16];
#pragma unroll
  for (int i = 0; i < 4; ++i) {
#pragma unroll
    for (int j = 0; j < 4; ++j) {
      size_t base = (size_t)(rowbase + i * 16) * NDIM + colbase + j * 16;
#pragma unroll
      for (int r = 0; r < 4; ++r)
        out[base + (size_t)r * NDIM] = acc[i][j][r] + bv[j];
    }
  }
}

extern "C" void kernel_launch(void* const* d_in, const int* in_sizes, int n_in,
                              void* d_out, int out_size, void* d_ws, size_t ws_size,
                              hipStream_t stream) {
  const float*    x      = (const float*)d_in[0];
  const uint32_t* wq     = (const uint32_t*)d_in[1];
  const float*    scales = (const float*)d_in[2];
  const float*    zeros  = (const float*)d_in[3];
  const float*    bias   = (const float*)d_in[4];
  float*          out    = (float*)d_out;

  const size_t offQ = 0;
  const size_t szQ  = (size_t)NDIM * KDIM;           // 45,088,768
  const size_t offX = szQ;
  const size_t szX  = (size_t)MDIM * KDIM;           // 16,777,216
  const size_t offD = offX + szX;                    // 61,865,984
  const size_t offS = offD + MDIM * sizeof(float);
  const size_t need = offS + MDIM * sizeof(float);   // ~61.9 MB

  if (ws_size >= need) {
    char*  Q8    = (char*)d_ws + offQ;
    char*  X8    = (char*)d_ws + offX;
    float* dlt   = (float*)((char*)d_ws + offD);
    float* xsm   = (float*)((char*)d_ws + offS);
    repack_q_kernel<<<(NDIM * KP) / 256, 256, 0, stream>>>(wq, (c8x8*)Q8);
    quant_x_kernel<<<MDIM, 256, 0, stream>>>(x, (c8x16*)X8, dlt, xsm);
    gemm_i8_kernel<<<688, 256, 0, stream>>>(X8, Q8, dlt, xsm, scales, zeros,
                                            bias, out);
  } else {
    gemm_fused_kernel<<<2752, 256, 0, stream>>>(x, wq, scales, zeros, bias, out);
  }
}